// Round 3
// baseline (73.632 us; speedup 1.0000x reference)
//
#include <hip/hip_runtime.h>

// Problem constants (from reference setup_inputs)
#define BB_ 16
#define LL_ 2048
#define DD_ 512
#define CC_ 64            // chunks along L
#define TT_ (LL_ / CC_)   // 32 steps per chunk

// Output y_t = stack[:, -1, :] obeys the first-order linear recurrence
//   y_t = a_t*y_{t-1} + g_t*x_t,  a=(1-p)(1-o), g=p(1-o), y_{-1}=0.
// Single-pass chained scan (decoupled lookback, rocPRIM-style):
// block (b,c) = blockIdx (c-major: predecessors have LOWER blockIdx, so the
// ascending HW dispatch order guarantees spin-wait forward progress).
//   pass 1: load x chunk into REGISTERS, local zero-seeded scan,
//           publish yend[b,c,:], Atot[b,c] + release flag (agent scope)
//   wait:   tid<c acquire-spin on predecessor flags
//   lookback: carry = sum over cp<c (fma chain with Atot products)
//   pass 2: rescan from registers seeded with carry, write out. x read ONCE.
__global__ __launch_bounds__(128) void stack_scan_kernel(
        const float* __restrict__ x,
        const float* __restrict__ push,
        const float* __restrict__ pop,
        float* __restrict__ yend,    // [B][C][D]
        float* __restrict__ Atot,    // [B][C]
        int*   __restrict__ flags,   // [B][C], zeroed before launch
        float* __restrict__ out) {
    int blk = blockIdx.x;
    int c = blk / BB_;      // chunk index — c-major ordering
    int b = blk % BB_;
    int t0 = c * TT_;
    int tid = threadIdx.x;  // 0..127, each owns 4 consecutive d (float4)

    __shared__ float sa[TT_];
    __shared__ float sb[TT_];
    __shared__ float sA[CC_];
    if (tid < TT_) {
        float p = push[b * LL_ + t0 + tid];
        float o = pop[b * LL_ + t0 + tid];
        float om = 1.0f - o;
        sa[tid] = (1.0f - p) * om;
        sb[tid] = p * om;
    }
    __syncthreads();

    // ---- pass 1: load x into registers, local scan ----
    const float4* xp = (const float4*)(x + ((size_t)b * LL_ + t0) * DD_) + tid;
    float4 xs[TT_];
    #pragma unroll
    for (int t = 0; t < TT_; ++t)
        xs[t] = xp[(size_t)t * (DD_ / 4)];

    float4 y = make_float4(0.f, 0.f, 0.f, 0.f);
    float pa = 1.0f;
    #pragma unroll
    for (int t = 0; t < TT_; ++t) {
        float a = sa[t];
        float g = sb[t];
        pa *= a;
        y.x = fmaf(a, y.x, g * xs[t].x);
        y.y = fmaf(a, y.y, g * xs[t].y);
        y.z = fmaf(a, y.z, g * xs[t].z);
        y.w = fmaf(a, y.w, g * xs[t].w);
    }

    // ---- publish partials (release, agent scope) ----
    ((float4*)(yend + ((size_t)b * CC_ + c) * DD_))[tid] = y;
    if (tid == 0) Atot[b * CC_ + c] = pa;
    __syncthreads();   // all publishes happen-before tid0's release store
    if (tid == 0)
        __hip_atomic_store(&flags[b * CC_ + c], 1,
                           __ATOMIC_RELEASE, __HIP_MEMORY_SCOPE_AGENT);

    // ---- wait for all predecessors (they all run concurrently) ----
    if (tid < c) {
        while (__hip_atomic_load(&flags[b * CC_ + tid],
                                 __ATOMIC_ACQUIRE, __HIP_MEMORY_SCOPE_AGENT) == 0)
            __builtin_amdgcn_s_sleep(2);
        sA[tid] = Atot[b * CC_ + tid];
    }
    __syncthreads();

    // ---- lookback: carry entering chunk c ----
    const float4* yp = (const float4*)(yend + (size_t)b * CC_ * DD_) + tid;
    float4 carry = make_float4(0.f, 0.f, 0.f, 0.f);
    #pragma unroll 4
    for (int cp = 0; cp < c; ++cp) {
        float4 v = yp[(size_t)cp * (DD_ / 4)];
        float A = sA[cp];
        carry.x = fmaf(A, carry.x, v.x);
        carry.y = fmaf(A, carry.y, v.y);
        carry.z = fmaf(A, carry.z, v.z);
        carry.w = fmaf(A, carry.w, v.w);
    }

    // ---- pass 2: final scan from registers, write output ----
    float4* op = (float4*)(out + ((size_t)b * LL_ + t0) * DD_) + tid;
    #pragma unroll
    for (int t = 0; t < TT_; ++t) {
        float a = sa[t];
        float g = sb[t];
        carry.x = fmaf(a, carry.x, g * xs[t].x);
        carry.y = fmaf(a, carry.y, g * xs[t].y);
        carry.z = fmaf(a, carry.z, g * xs[t].z);
        carry.w = fmaf(a, carry.w, g * xs[t].w);
        op[(size_t)t * (DD_ / 4)] = carry;
    }
}

extern "C" void kernel_launch(void* const* d_in, const int* in_sizes, int n_in,
                              void* d_out, int out_size, void* d_ws, size_t ws_size,
                              hipStream_t stream) {
    const float* x    = (const float*)d_in[0];
    const float* push = (const float*)d_in[1];
    const float* pop  = (const float*)d_in[2];
    float* out = (float*)d_out;

    // Workspace layout:
    //   flags : B*C ints  = 4 KiB   (must be zeroed every call)
    //   Atot  : B*C float = 4 KiB
    //   yend  : B*C*D     = 2 MiB
    int*   flags = (int*)d_ws;
    float* Atot  = (float*)d_ws + BB_ * CC_;
    float* yend  = (float*)d_ws + 2 * BB_ * CC_;

    hipMemsetAsync(flags, 0, BB_ * CC_ * sizeof(int), stream);
    stack_scan_kernel<<<BB_ * CC_, 128, 0, stream>>>(x, push, pop,
                                                     yend, Atot, flags, out);
}